// Round 3
// baseline (9319.330 us; speedup 1.0000x reference)
//
#include <hip/hip_runtime.h>
#include <hip/hip_bf16.h>

// TemporalGNN: GRU's H stays zero => R dead, timesteps independent.
// out[b,n,:] = relu( sum_t p_t*(1-Z_t)*Ht_t ) @ W_out + b_out
//   Z  = sigmoid(Y_t @ Wz + bz),  Ht = tanh(Y_t @ Wh + bh)
//   Y_t = sym-normalized aggregation of X[...,t] in F=32 space.
// k_main: persistent waves; wave owns (n,b); Y row in registers/LDS slice.

#define FDIM 32
#define TDIM 12
#define ODIM 64
#define BDIM 4

__global__ void k_count(const int* __restrict__ dst, int* __restrict__ counts, int E) {
    int e = blockIdx.x * 256 + threadIdx.x;
    if (e < E) atomicAdd(&counts[dst[e]], 1);
}

__global__ __launch_bounds__(1024) void k_scan(const int* __restrict__ counts,
                                               int* __restrict__ offsets,
                                               float* __restrict__ dis, int N) {
    __shared__ int wsum[16];
    __shared__ int sCarry;
    const int tid = threadIdx.x;
    const int lane = tid & 63;
    const int wv = tid >> 6;
    if (tid == 0) sCarry = 0;
    __syncthreads();
    for (int base = 0; base < N; base += 1024) {
        int i = base + tid;
        int v = (i < N) ? counts[i] : 0;
        int s = v;
        for (int off = 1; off < 64; off <<= 1) {
            int t = __shfl_up(s, off, 64);
            if (lane >= off) s += t;
        }
        if (lane == 63) wsum[wv] = s;
        __syncthreads();
        if (wv == 0 && lane < 16) {
            int ws = wsum[lane];
            for (int off = 1; off < 16; off <<= 1) {
                int t = __shfl_up(ws, off, 64);
                if (lane >= off) ws += t;
            }
            wsum[lane] = ws;
        }
        __syncthreads();
        int carry = sCarry;
        int wpre = (wv > 0) ? wsum[wv - 1] : 0;
        if (i < N) {
            offsets[i] = carry + wpre + s - v;
            dis[i] = 1.0f / sqrtf((float)(v + 1));
        }
        __syncthreads();
        if (tid == 0) sCarry = carry + wsum[15];
        __syncthreads();
    }
    if (tid == 0) offsets[N] = sCarry;
}

__global__ void k_scatter(const int* __restrict__ src, const int* __restrict__ dst,
                          const int* __restrict__ offsets, int* __restrict__ fill,
                          const float* __restrict__ dis,
                          int2* __restrict__ csr, int E) {
    int e = blockIdx.x * 256 + threadIdx.x;
    if (e < E) {
        int s = src[e], d = dst[e];
        int pos = offsets[d] + atomicAdd(&fill[d], 1);
        csr[pos] = make_int2(s, __float_as_int(dis[s] * dis[d]));
    }
}

__global__ void k_prep(const float* __restrict__ Wg_z, const float* __restrict__ bg_z,
                       const float* __restrict__ Wl_z, const float* __restrict__ bl_z,
                       const float* __restrict__ Wg_h, const float* __restrict__ bg_h,
                       const float* __restrict__ Wl_h, const float* __restrict__ bl_h,
                       const float* __restrict__ att,
                       float* __restrict__ Wz, float* __restrict__ bz,
                       float* __restrict__ Wh, float* __restrict__ bh,
                       float* __restrict__ probs) {
    int tid = threadIdx.x;
    for (int i = tid; i < FDIM * ODIM; i += 256) {
        int f = i >> 6, o = i & 63;
        float az = 0.f, ah = 0.f;
        for (int k = 0; k < ODIM; k++) {
            az += Wg_z[f * ODIM + k] * Wl_z[k * ODIM + o];
            ah += Wg_h[f * ODIM + k] * Wl_h[k * ODIM + o];
        }
        Wz[i] = az;
        Wh[i] = ah;
    }
    if (tid < ODIM) {
        float az = bl_z[tid], ah = bl_h[tid];
        for (int k = 0; k < ODIM; k++) {
            az += bg_z[k] * Wl_z[k * ODIM + tid];
            ah += bg_h[k] * Wl_h[k * ODIM + tid];
        }
        bz[tid] = az;
        bh[tid] = ah;
    }
    if (tid == 0) {
        float m = -1e30f;
        for (int t = 0; t < TDIM; t++) m = fmaxf(m, att[t]);
        float e[TDIM], s = 0.f;
        for (int t = 0; t < TDIM; t++) { e[t] = expf(att[t] - m); s += e[t]; }
        for (int t = 0; t < TDIM; t++) probs[t] = e[t] / s;
    }
}

__device__ __forceinline__ float sigm(float x) { return 1.f / (1.f + expf(-x)); }

// Persistent-wave kernel: wave = one (node, batch) task, grid-stride.
// Lanes hold the 384-float Y row as 3 float2 each (flat idx f*T+t).
__global__ __launch_bounds__(256, 3) void k_main(
    const float* __restrict__ X, const int* __restrict__ offsets,
    const int2* __restrict__ csr, const float* __restrict__ dis,
    const float* __restrict__ Wz, const float* __restrict__ bz,
    const float* __restrict__ Wh, const float* __restrict__ bh,
    const float* __restrict__ probs, const float* __restrict__ Wout,
    const float* __restrict__ bout, float* __restrict__ out, int N) {
    __shared__ float sY[4][FDIM * TDIM];   // 6 KiB: per-wave Y slice
    const int tid = threadIdx.x;
    const int wv = tid >> 6, lane = tid & 63;
    float* __restrict__ sYw = sY[wv];

    // ---- per-wave persistent state (loaded once) ----
    float wzr[FDIM], whr[FDIM];
#pragma unroll
    for (int f = 0; f < FDIM; f++) {
        wzr[f] = Wz[f * ODIM + lane];
        whr[f] = Wh[f * ODIM + lane];
    }
    const float bzo = bz[lane], bho = bh[lane];
    float wout_r[TDIM];
#pragma unroll
    for (int j = 0; j < TDIM; j++) wout_r[j] = Wout[lane * TDIM + j];
    float pr[TDIM];
#pragma unroll
    for (int j = 0; j < TDIM; j++) pr[j] = probs[j];
    const float bo = (lane < TDIM) ? bout[lane] : 0.f;

    const float2* __restrict__ X2 = (const float2*)X;
    const int totalTasks = N * BDIM;
    const int stride = gridDim.x * 4;

    for (int task = blockIdx.x * 4 + wv; task < totalTasks; task += stride) {
        const int n = task >> 2;          // same n for all 4 waves of a block
        const int b = task & 3;           // == wv
        const int beg = offsets[n], end = offsets[n + 1];
        const float dn = dis[n];
        const float snorm = dn * dn;

        // ---- aggregation: Y = snorm*X[b,n] + sum_e nm*X[b,src] ----
        const unsigned selfBase = (unsigned)(b * N + n) * 192u;
        float2 y0 = X2[selfBase + lane];
        float2 y1 = X2[selfBase + 64 + lane];
        float2 y2 = X2[selfBase + 128 + lane];
        y0.x *= snorm; y0.y *= snorm;
        y1.x *= snorm; y1.y *= snorm;
        y2.x *= snorm; y2.y *= snorm;

        for (int ebase = beg; ebase < end; ebase += 64) {
            const int cnt = min(64, end - ebase);
            int esrc = 0; float enm = 0.f;
            if (ebase + lane < end) {
                int2 e = csr[ebase + lane];   // one coalesced load for all edges
                esrc = e.x; enm = __int_as_float(e.y);
            }
            int j = 0;
            for (; j + 4 <= cnt; j += 4) {
                const int s0 = __shfl(esrc, j + 0, 64), s1 = __shfl(esrc, j + 1, 64);
                const int s2 = __shfl(esrc, j + 2, 64), s3 = __shfl(esrc, j + 3, 64);
                const float m0 = __shfl(enm, j + 0, 64), m1 = __shfl(enm, j + 1, 64);
                const float m2 = __shfl(enm, j + 2, 64), m3 = __shfl(enm, j + 3, 64);
                const unsigned r0 = (unsigned)(b * N + s0) * 192u;
                const unsigned r1 = (unsigned)(b * N + s1) * 192u;
                const unsigned r2 = (unsigned)(b * N + s2) * 192u;
                const unsigned r3 = (unsigned)(b * N + s3) * 192u;
                const float2 a00 = X2[r0 + lane], a01 = X2[r0 + 64 + lane], a02 = X2[r0 + 128 + lane];
                const float2 a10 = X2[r1 + lane], a11 = X2[r1 + 64 + lane], a12 = X2[r1 + 128 + lane];
                const float2 a20 = X2[r2 + lane], a21 = X2[r2 + 64 + lane], a22 = X2[r2 + 128 + lane];
                const float2 a30 = X2[r3 + lane], a31 = X2[r3 + 64 + lane], a32 = X2[r3 + 128 + lane];
                y0.x += m0 * a00.x; y0.y += m0 * a00.y;
                y1.x += m0 * a01.x; y1.y += m0 * a01.y;
                y2.x += m0 * a02.x; y2.y += m0 * a02.y;
                y0.x += m1 * a10.x; y0.y += m1 * a10.y;
                y1.x += m1 * a11.x; y1.y += m1 * a11.y;
                y2.x += m1 * a12.x; y2.y += m1 * a12.y;
                y0.x += m2 * a20.x; y0.y += m2 * a20.y;
                y1.x += m2 * a21.x; y1.y += m2 * a21.y;
                y2.x += m2 * a22.x; y2.y += m2 * a22.y;
                y0.x += m3 * a30.x; y0.y += m3 * a30.y;
                y1.x += m3 * a31.x; y1.y += m3 * a31.y;
                y2.x += m3 * a32.x; y2.y += m3 * a32.y;
            }
            for (; j < cnt; j++) {
                const int s = __shfl(esrc, j, 64);
                const float m = __shfl(enm, j, 64);
                const unsigned r = (unsigned)(b * N + s) * 192u;
                const float2 a0 = X2[r + lane], a1 = X2[r + 64 + lane], a2 = X2[r + 128 + lane];
                y0.x += m * a0.x; y0.y += m * a0.y;
                y1.x += m * a1.x; y1.y += m * a1.y;
                y2.x += m * a2.x; y2.y += m * a2.y;
            }
        }

        // ---- publish Y to this wave's LDS slice ----
        float2* sY2 = (float2*)sYw;
        sY2[lane] = y0;
        sY2[64 + lane] = y1;
        sY2[128 + lane] = y2;
        __syncthreads();   // block's 4 waves share n => same trip counts

        // ---- gates: lane = o; t processed 4 at a time via float4 broadcast ----
        float acc = 0.f;
        const float4* __restrict__ sY4 = (const float4*)sYw;
#pragma unroll
        for (int tq = 0; tq < 3; tq++) {
            float z0 = bzo, z1 = bzo, z2 = bzo, z3 = bzo;
            float h0 = bho, h1 = bho, h2 = bho, h3 = bho;
#pragma unroll
            for (int f = 0; f < FDIM; f++) {
                const float4 y4 = sY4[f * 3 + tq];   // floats [f*12 + 4tq ..]
                z0 += y4.x * wzr[f]; h0 += y4.x * whr[f];
                z1 += y4.y * wzr[f]; h1 += y4.y * whr[f];
                z2 += y4.z * wzr[f]; h2 += y4.z * whr[f];
                z3 += y4.w * wzr[f]; h3 += y4.w * whr[f];
            }
            const int t = tq * 4;
            acc += pr[t + 0] * (1.f - sigm(z0)) * tanhf(h0);
            acc += pr[t + 1] * (1.f - sigm(z1)) * tanhf(h1);
            acc += pr[t + 2] * (1.f - sigm(z2)) * tanhf(h2);
            acc += pr[t + 3] * (1.f - sigm(z3)) * tanhf(h3);
        }
        __syncthreads();   // done reading sYw before next iteration overwrites

        // ---- readout: shuffle-butterfly reduce relu(acc)*Wout over o ----
        const float r = fmaxf(acc, 0.f);
        float v[TDIM];
#pragma unroll
        for (int j = 0; j < TDIM; j++) v[j] = r * wout_r[j];
#pragma unroll
        for (int m = 1; m < 64; m <<= 1) {
#pragma unroll
            for (int j = 0; j < TDIM; j++) v[j] += __shfl_xor(v[j], m, 64);
        }
        if (lane < TDIM) {
            float vj = 0.f;
#pragma unroll
            for (int j = 0; j < TDIM; j++) vj = (lane == j) ? v[j] : vj;
            out[(unsigned)(b * N + n) * TDIM + lane] = vj + bo;
        }
    }
}

extern "C" void kernel_launch(void* const* d_in, const int* in_sizes, int n_in,
                              void* d_out, int out_size, void* d_ws, size_t ws_size,
                              hipStream_t stream) {
    const float* X    = (const float*)d_in[0];
    const int*   ei   = (const int*)d_in[1];
    const float* Wg_z = (const float*)d_in[2];
    const float* bg_z = (const float*)d_in[3];
    const float* Wg_h = (const float*)d_in[6];
    const float* bg_h = (const float*)d_in[7];
    const float* Wl_z = (const float*)d_in[8];
    const float* bl_z = (const float*)d_in[9];
    const float* Wl_h = (const float*)d_in[12];
    const float* bl_h = (const float*)d_in[13];
    const float* att  = (const float*)d_in[14];
    const float* Wout = (const float*)d_in[15];
    const float* bout = (const float*)d_in[16];
    float* out = (float*)d_out;

    const int E = in_sizes[1] / 2;
    const int N = in_sizes[0] / (BDIM * FDIM * TDIM);

    char* wp = (char*)d_ws;
    int* counts   = (int*)wp;   wp += (size_t)N * 4;
    int* fill     = (int*)wp;   wp += (size_t)N * 4;
    int* offs     = (int*)wp;   wp += (size_t)(N + 4) * 4;
    float* dis    = (float*)wp; wp += (size_t)N * 4;
    int2* csr     = (int2*)wp;  wp += (size_t)E * 8;
    float* Wz     = (float*)wp; wp += FDIM * ODIM * 4;
    float* Wh     = (float*)wp; wp += FDIM * ODIM * 4;
    float* bz     = (float*)wp; wp += ODIM * 4;
    float* bh     = (float*)wp; wp += ODIM * 4;
    float* probs  = (float*)wp; wp += 16 * 4;

    hipMemsetAsync(counts, 0, (size_t)2 * N * 4, stream);

    k_prep<<<1, 256, 0, stream>>>(Wg_z, bg_z, Wl_z, bl_z, Wg_h, bg_h, Wl_h, bl_h,
                                  att, Wz, bz, Wh, bh, probs);
    k_count<<<(E + 255) / 256, 256, 0, stream>>>(ei + E, counts, E);
    k_scan<<<1, 1024, 0, stream>>>(counts, offs, dis, N);
    k_scatter<<<(E + 255) / 256, 256, 0, stream>>>(ei, ei + E, offs, fill, dis, csr, E);

    const int totalTasks = N * BDIM;
    int nBlocks = (totalTasks + 3) / 4;
    if (nBlocks > 2048) nBlocks = 2048;
    k_main<<<nBlocks, 256, 0, stream>>>(X, offs, csr, dis, Wz, bz, Wh, bh,
                                        probs, Wout, bout, out, N);
}

// Round 4
// 1167.712 us; speedup vs baseline: 7.9808x; 7.9808x over previous
//
#include <hip/hip_runtime.h>
#include <hip/hip_bf16.h>

// TemporalGNN: GRU's H stays zero => R dead, timesteps independent.
// out[b,n,:] = relu( sum_t p_t*(1-Z_t)*Ht_t ) @ W_out + b_out
//   Z  = sigmoid(Y_t @ Wz + bz),  Ht = tanh(Y_t @ Wh + bh)
//   Y_t = sym-normalized aggregation of X[...,t] in F=32 space.
// k_main: persistent block-per-node (R2 gather structure), weights hoisted.

#define FDIM 32
#define TDIM 12
#define ODIM 64
#define BDIM 4

__global__ void k_count(const int* __restrict__ dst, int* __restrict__ counts, int E) {
    int e = blockIdx.x * 256 + threadIdx.x;
    if (e < E) atomicAdd(&counts[dst[e]], 1);
}

__global__ __launch_bounds__(1024) void k_scan(const int* __restrict__ counts,
                                               int* __restrict__ offsets,
                                               float* __restrict__ dis, int N) {
    __shared__ int wsum[16];
    __shared__ int sCarry;
    const int tid = threadIdx.x;
    const int lane = tid & 63;
    const int wv = tid >> 6;
    if (tid == 0) sCarry = 0;
    __syncthreads();
    for (int base = 0; base < N; base += 1024) {
        int i = base + tid;
        int v = (i < N) ? counts[i] : 0;
        int s = v;
        for (int off = 1; off < 64; off <<= 1) {
            int t = __shfl_up(s, off, 64);
            if (lane >= off) s += t;
        }
        if (lane == 63) wsum[wv] = s;
        __syncthreads();
        if (wv == 0 && lane < 16) {
            int ws = wsum[lane];
            for (int off = 1; off < 16; off <<= 1) {
                int t = __shfl_up(ws, off, 64);
                if (lane >= off) ws += t;
            }
            wsum[lane] = ws;
        }
        __syncthreads();
        int carry = sCarry;
        int wpre = (wv > 0) ? wsum[wv - 1] : 0;
        if (i < N) {
            offsets[i] = carry + wpre + s - v;
            dis[i] = 1.0f / sqrtf((float)(v + 1));
        }
        __syncthreads();
        if (tid == 0) sCarry = carry + wsum[15];
        __syncthreads();
    }
    if (tid == 0) offsets[N] = sCarry;
}

__global__ void k_scatter(const int* __restrict__ src, const int* __restrict__ dst,
                          const int* __restrict__ offsets, int* __restrict__ fill,
                          const float* __restrict__ dis,
                          int2* __restrict__ csr, int E) {
    int e = blockIdx.x * 256 + threadIdx.x;
    if (e < E) {
        int s = src[e], d = dst[e];
        int pos = offsets[d] + atomicAdd(&fill[d], 1);
        csr[pos] = make_int2(s, __float_as_int(dis[s] * dis[d]));
    }
}

__global__ void k_prep(const float* __restrict__ Wg_z, const float* __restrict__ bg_z,
                       const float* __restrict__ Wl_z, const float* __restrict__ bl_z,
                       const float* __restrict__ Wg_h, const float* __restrict__ bg_h,
                       const float* __restrict__ Wl_h, const float* __restrict__ bl_h,
                       const float* __restrict__ att,
                       float* __restrict__ Wz, float* __restrict__ bz,
                       float* __restrict__ Wh, float* __restrict__ bh,
                       float* __restrict__ probs) {
    int tid = threadIdx.x;
    for (int i = tid; i < FDIM * ODIM; i += 256) {
        int f = i >> 6, o = i & 63;
        float az = 0.f, ah = 0.f;
        for (int k = 0; k < ODIM; k++) {
            az += Wg_z[f * ODIM + k] * Wl_z[k * ODIM + o];
            ah += Wg_h[f * ODIM + k] * Wl_h[k * ODIM + o];
        }
        Wz[i] = az;
        Wh[i] = ah;
    }
    if (tid < ODIM) {
        float az = bl_z[tid], ah = bl_h[tid];
        for (int k = 0; k < ODIM; k++) {
            az += bg_z[k] * Wl_z[k * ODIM + tid];
            ah += bg_h[k] * Wl_h[k * ODIM + tid];
        }
        bz[tid] = az;
        bh[tid] = ah;
    }
    if (tid == 0) {
        float m = -1e30f;
        for (int t = 0; t < TDIM; t++) m = fmaxf(m, att[t]);
        float e[TDIM], s = 0.f;
        for (int t = 0; t < TDIM; t++) { e[t] = expf(att[t] - m); s += e[t]; }
        for (int t = 0; t < TDIM; t++) probs[t] = e[t] / s;
    }
}

__device__ __forceinline__ float sigm(float x) { return 1.f / (1.f + expf(-x)); }

// Persistent block-per-node. 384 threads = 6 waves.
// Phase 1: thread owns (batch b, float4-chunk q of 96): gather neighbors.
//          Edges read straight from csr (wave-uniform broadcast loads).
// Phase 2: thread (o=tid&63, w=tid>>6) computes gates for t=w and t=w+6.
// Phase 3: tid<48 does ReLU + 64->12 readout from LDS-staged Wout.
__global__ __launch_bounds__(384, 3) void k_main(
    const float* __restrict__ X, const int* __restrict__ offsets,
    const int2* __restrict__ csr, const float* __restrict__ dis,
    const float* __restrict__ Wz, const float* __restrict__ bz,
    const float* __restrict__ Wh, const float* __restrict__ bh,
    const float* __restrict__ probs, const float* __restrict__ Wout,
    const float* __restrict__ bout, float* __restrict__ out, int N) {
    const int tid = threadIdx.x;

    __shared__ float4 sY4[BDIM][96];    // 6 KiB
    __shared__ float sAcc[BDIM][ODIM];  // 1 KiB
    __shared__ float sWout[ODIM * TDIM];// 3 KiB
    __shared__ float sBout[TDIM];

    // ---- per-block persistent state (once) ----
    for (int i = tid; i < ODIM * TDIM; i += 384) sWout[i] = Wout[i];
    if (tid < TDIM) sBout[tid] = bout[tid];

    const int o = tid & 63;
    const int w = tid >> 6;
    float wzr[FDIM], whr[FDIM];
#pragma unroll
    for (int f = 0; f < FDIM; f++) {
        wzr[f] = Wz[f * ODIM + o];
        whr[f] = Wh[f * ODIM + o];
    }
    const float bzo = bz[o], bho = bh[o];
    const int t0 = w, t1 = w + 6;
    const float p0 = probs[t0], p1 = probs[t1];

    const int b = tid / 96;
    const int q = tid - b * 96;
    const float4* __restrict__ Xq = (const float4*)X;

    for (int n = blockIdx.x; n < N; n += gridDim.x) {
        if (tid < BDIM * ODIM) ((float*)sAcc)[tid] = 0.f;  // safe: barrier below precedes atomics

        const int beg = offsets[n], end = offsets[n + 1];
        const float dn = dis[n];
        const float snorm = dn * dn;

        // ---- Phase 1: gather ----
        float4 a0 = Xq[(unsigned)(b * N + n) * 96u + q];
        a0.x *= snorm; a0.y *= snorm; a0.z *= snorm; a0.w *= snorm;
        float4 a1 = make_float4(0.f, 0.f, 0.f, 0.f);
        float4 a2 = make_float4(0.f, 0.f, 0.f, 0.f);
        float4 a3 = make_float4(0.f, 0.f, 0.f, 0.f);

        int j = beg;
        for (; j + 4 <= end; j += 4) {
            const int2 e0 = csr[j], e1 = csr[j + 1], e2 = csr[j + 2], e3 = csr[j + 3];
            const float4 v0 = Xq[(unsigned)(b * N + e0.x) * 96u + q];
            const float4 v1 = Xq[(unsigned)(b * N + e1.x) * 96u + q];
            const float4 v2 = Xq[(unsigned)(b * N + e2.x) * 96u + q];
            const float4 v3 = Xq[(unsigned)(b * N + e3.x) * 96u + q];
            const float n0 = __int_as_float(e0.y), n1 = __int_as_float(e1.y);
            const float n2 = __int_as_float(e2.y), n3 = __int_as_float(e3.y);
            a0.x += n0 * v0.x; a0.y += n0 * v0.y; a0.z += n0 * v0.z; a0.w += n0 * v0.w;
            a1.x += n1 * v1.x; a1.y += n1 * v1.y; a1.z += n1 * v1.z; a1.w += n1 * v1.w;
            a2.x += n2 * v2.x; a2.y += n2 * v2.y; a2.z += n2 * v2.z; a2.w += n2 * v2.w;
            a3.x += n3 * v3.x; a3.y += n3 * v3.y; a3.z += n3 * v3.z; a3.w += n3 * v3.w;
        }
        for (; j < end; j++) {
            const int2 e = csr[j];
            const float4 v = Xq[(unsigned)(b * N + e.x) * 96u + q];
            const float nm = __int_as_float(e.y);
            a0.x += nm * v.x; a0.y += nm * v.y; a0.z += nm * v.z; a0.w += nm * v.w;
        }
        a0.x += (a1.x + a2.x) + a3.x;
        a0.y += (a1.y + a2.y) + a3.y;
        a0.z += (a1.z + a2.z) + a3.z;
        a0.w += (a1.w + a2.w) + a3.w;
        sY4[b][q] = a0;
        __syncthreads();

        // ---- Phase 2: gates ----
#pragma unroll
        for (int bb = 0; bb < BDIM; bb++) {
            const float* yb = (const float*)sY4[bb];
            float z0 = bzo, z1 = bzo, h0 = bho, h1 = bho;
#pragma unroll
            for (int f = 0; f < FDIM; f++) {
                float ya = yb[f * TDIM + t0];
                float yc = yb[f * TDIM + t1];
                z0 += ya * wzr[f]; h0 += ya * whr[f];
                z1 += yc * wzr[f]; h1 += yc * whr[f];
            }
            float contrib = p0 * (1.f - sigm(z0)) * tanhf(h0)
                          + p1 * (1.f - sigm(z1)) * tanhf(h1);
            atomicAdd(&sAcc[bb][o], contrib);
        }
        __syncthreads();

        // ---- Phase 3: readout ----
        if (tid < BDIM * TDIM) {
            int ob = tid / TDIM, jj = tid - ob * TDIM;
            float v = sBout[jj];
#pragma unroll
            for (int o2 = 0; o2 < ODIM; o2++) {
                v += fmaxf(sAcc[ob][o2], 0.f) * sWout[o2 * TDIM + jj];
            }
            out[(unsigned)(ob * N + n) * TDIM + jj] = v;
        }
        __syncthreads();  // protect sAcc/sY4 for next iteration
    }
}

extern "C" void kernel_launch(void* const* d_in, const int* in_sizes, int n_in,
                              void* d_out, int out_size, void* d_ws, size_t ws_size,
                              hipStream_t stream) {
    const float* X    = (const float*)d_in[0];
    const int*   ei   = (const int*)d_in[1];
    const float* Wg_z = (const float*)d_in[2];
    const float* bg_z = (const float*)d_in[3];
    const float* Wg_h = (const float*)d_in[6];
    const float* bg_h = (const float*)d_in[7];
    const float* Wl_z = (const float*)d_in[8];
    const float* bl_z = (const float*)d_in[9];
    const float* Wl_h = (const float*)d_in[12];
    const float* bl_h = (const float*)d_in[13];
    const float* att  = (const float*)d_in[14];
    const float* Wout = (const float*)d_in[15];
    const float* bout = (const float*)d_in[16];
    float* out = (float*)d_out;

    const int E = in_sizes[1] / 2;
    const int N = in_sizes[0] / (BDIM * FDIM * TDIM);

    char* wp = (char*)d_ws;
    int* counts   = (int*)wp;   wp += (size_t)N * 4;
    int* fill     = (int*)wp;   wp += (size_t)N * 4;
    int* offs     = (int*)wp;   wp += (size_t)(N + 4) * 4;
    float* dis    = (float*)wp; wp += (size_t)N * 4;
    int2* csr     = (int2*)wp;  wp += (size_t)E * 8;
    float* Wz     = (float*)wp; wp += FDIM * ODIM * 4;
    float* Wh     = (float*)wp; wp += FDIM * ODIM * 4;
    float* bz     = (float*)wp; wp += ODIM * 4;
    float* bh     = (float*)wp; wp += ODIM * 4;
    float* probs  = (float*)wp; wp += 16 * 4;

    hipMemsetAsync(counts, 0, (size_t)2 * N * 4, stream);

    k_prep<<<1, 256, 0, stream>>>(Wg_z, bg_z, Wl_z, bl_z, Wg_h, bg_h, Wl_h, bl_h,
                                  att, Wz, bz, Wh, bh, probs);
    k_count<<<(E + 255) / 256, 256, 0, stream>>>(ei + E, counts, E);
    k_scan<<<1, 1024, 0, stream>>>(counts, offs, dis, N);
    k_scatter<<<(E + 255) / 256, 256, 0, stream>>>(ei, ei + E, offs, fill, dis, csr, E);

    int nBlocks = N < 1024 ? N : 1024;
    k_main<<<nBlocks, 384, 0, stream>>>(X, offs, csr, dis, Wz, bz, Wh, bh,
                                        probs, Wout, bout, out, N);
}

// Round 5
// 1166.051 us; speedup vs baseline: 7.9922x; 1.0014x over previous
//
#include <hip/hip_runtime.h>
#include <hip/hip_bf16.h>

// TemporalGNN: GRU's H stays zero => R dead, timesteps independent.
// out[b,n,:] = relu( sum_t p_t*(1-Z_t)*Ht_t ) @ W_out + b_out
//   Z  = sigmoid(Y_t @ Wz + bz),  Ht = tanh(Y_t @ Wh + bh)
//   Y_t = sym-normalized aggregation of X[...,t] in F=32 space.
// k_main: block-per-node grid-stride; edges shfl-broadcast; 8-deep gather MLP.

#define FDIM 32
#define TDIM 12
#define ODIM 64
#define BDIM 4

__global__ void k_count(const int* __restrict__ dst, int* __restrict__ counts, int E) {
    int e = blockIdx.x * 256 + threadIdx.x;
    if (e < E) atomicAdd(&counts[dst[e]], 1);
}

__global__ __launch_bounds__(1024) void k_scan(const int* __restrict__ counts,
                                               int* __restrict__ offsets,
                                               float* __restrict__ dis, int N) {
    __shared__ int wsum[16];
    __shared__ int sCarry;
    const int tid = threadIdx.x;
    const int lane = tid & 63;
    const int wv = tid >> 6;
    if (tid == 0) sCarry = 0;
    __syncthreads();
    for (int base = 0; base < N; base += 1024) {
        int i = base + tid;
        int v = (i < N) ? counts[i] : 0;
        int s = v;
        for (int off = 1; off < 64; off <<= 1) {
            int t = __shfl_up(s, off, 64);
            if (lane >= off) s += t;
        }
        if (lane == 63) wsum[wv] = s;
        __syncthreads();
        if (wv == 0 && lane < 16) {
            int ws = wsum[lane];
            for (int off = 1; off < 16; off <<= 1) {
                int t = __shfl_up(ws, off, 64);
                if (lane >= off) ws += t;
            }
            wsum[lane] = ws;
        }
        __syncthreads();
        int carry = sCarry;
        int wpre = (wv > 0) ? wsum[wv - 1] : 0;
        if (i < N) {
            offsets[i] = carry + wpre + s - v;
            dis[i] = 1.0f / sqrtf((float)(v + 1));
        }
        __syncthreads();
        if (tid == 0) sCarry = carry + wsum[15];
        __syncthreads();
    }
    if (tid == 0) offsets[N] = sCarry;
}

__global__ void k_scatter(const int* __restrict__ src, const int* __restrict__ dst,
                          const int* __restrict__ offsets, int* __restrict__ fill,
                          const float* __restrict__ dis,
                          int2* __restrict__ csr, int E) {
    int e = blockIdx.x * 256 + threadIdx.x;
    if (e < E) {
        int s = src[e], d = dst[e];
        int pos = offsets[d] + atomicAdd(&fill[d], 1);
        csr[pos] = make_int2(s, __float_as_int(dis[s] * dis[d]));
    }
}

__global__ void k_prep(const float* __restrict__ Wg_z, const float* __restrict__ bg_z,
                       const float* __restrict__ Wl_z, const float* __restrict__ bl_z,
                       const float* __restrict__ Wg_h, const float* __restrict__ bg_h,
                       const float* __restrict__ Wl_h, const float* __restrict__ bl_h,
                       const float* __restrict__ att,
                       float* __restrict__ Wz, float* __restrict__ bz,
                       float* __restrict__ Wh, float* __restrict__ bh,
                       float* __restrict__ probs) {
    int tid = threadIdx.x;
    for (int i = tid; i < FDIM * ODIM; i += 256) {
        int f = i >> 6, o = i & 63;
        float az = 0.f, ah = 0.f;
        for (int k = 0; k < ODIM; k++) {
            az += Wg_z[f * ODIM + k] * Wl_z[k * ODIM + o];
            ah += Wg_h[f * ODIM + k] * Wl_h[k * ODIM + o];
        }
        Wz[i] = az;
        Wh[i] = ah;
    }
    if (tid < ODIM) {
        float az = bl_z[tid], ah = bl_h[tid];
        for (int k = 0; k < ODIM; k++) {
            az += bg_z[k] * Wl_z[k * ODIM + tid];
            ah += bg_h[k] * Wl_h[k * ODIM + tid];
        }
        bz[tid] = az;
        bh[tid] = ah;
    }
    if (tid == 0) {
        float m = -1e30f;
        for (int t = 0; t < TDIM; t++) m = fmaxf(m, att[t]);
        float e[TDIM], s = 0.f;
        for (int t = 0; t < TDIM; t++) { e[t] = expf(att[t] - m); s += e[t]; }
        for (int t = 0; t < TDIM; t++) probs[t] = e[t] / s;
    }
}

__device__ __forceinline__ float sigm(float x) { return 1.f / (1.f + expf(-x)); }

// Block-per-node, grid-stride. 384 threads = 6 waves.
// Phase 1: thread owns (batch b = tid/96, float4-chunk q = tid%96).
//          Edge list loaded ONCE per wave (coalesced int2), edges broadcast
//          via __shfl; gather loop has zero dependent memory ops, 8 deep.
// Phase 2: thread (o=tid&63, w=tid>>6) computes gates for t=w, w+6.
// Phase 3: tid<48 does ReLU + 64->12 readout.
__global__ __launch_bounds__(384) void k_main(
    const float* __restrict__ X, const int* __restrict__ offsets,
    const int2* __restrict__ csr, const float* __restrict__ dis,
    const float* __restrict__ Wz, const float* __restrict__ bz,
    const float* __restrict__ Wh, const float* __restrict__ bh,
    const float* __restrict__ probs, const float* __restrict__ Wout,
    const float* __restrict__ bout, float* __restrict__ out, int N) {
    const int tid = threadIdx.x;
    const int lane = tid & 63;

    __shared__ float4 sY4[BDIM][96];    // 6 KiB
    __shared__ float sAcc[BDIM][ODIM];  // 1 KiB
    __shared__ float sWout[ODIM * TDIM];// 3 KiB
    __shared__ float sBout[TDIM];

    for (int i = tid; i < ODIM * TDIM; i += 384) sWout[i] = Wout[i];
    if (tid < TDIM) sBout[tid] = bout[tid];

    const int o = tid & 63;
    const int w = tid >> 6;
    float wzr[FDIM], whr[FDIM];
#pragma unroll
    for (int f = 0; f < FDIM; f++) {
        wzr[f] = Wz[f * ODIM + o];
        whr[f] = Wh[f * ODIM + o];
    }
    const float bzo = bz[o], bho = bh[o];
    const int t0 = w, t1 = w + 6;
    const float p0 = probs[t0], p1 = probs[t1];

    const int b = tid / 96;
    const int q = tid - b * 96;
    const float4* __restrict__ Xq = (const float4*)X;
    const unsigned rowBase = (unsigned)b * (unsigned)N;

    for (int n = blockIdx.x; n < N; n += gridDim.x) {
        if (tid < BDIM * ODIM) ((float*)sAcc)[tid] = 0.f;

        const int beg = offsets[n], end = offsets[n + 1];
        const float dn = dis[n];
        const float snorm = dn * dn;

        // ---- Phase 1: gather ----
        float4 a0 = Xq[(rowBase + n) * 96u + q];
        a0.x *= snorm; a0.y *= snorm; a0.z *= snorm; a0.w *= snorm;
        float4 a1 = make_float4(0.f, 0.f, 0.f, 0.f);
        float4 a2 = make_float4(0.f, 0.f, 0.f, 0.f);
        float4 a3 = make_float4(0.f, 0.f, 0.f, 0.f);

        for (int ebase = beg; ebase < end; ebase += 64) {
            const int cnt = min(64, end - ebase);
            int esrc = 0;
            float enm = 0.f;
            if (ebase + lane < end) {            // one coalesced load per wave
                const int2 e = csr[ebase + lane];
                esrc = e.x;
                enm = __int_as_float(e.y);
            }
            int j = 0;
            for (; j + 8 <= cnt; j += 8) {
                const int s0 = __shfl(esrc, j + 0, 64), s1 = __shfl(esrc, j + 1, 64);
                const int s2 = __shfl(esrc, j + 2, 64), s3 = __shfl(esrc, j + 3, 64);
                const int s4 = __shfl(esrc, j + 4, 64), s5 = __shfl(esrc, j + 5, 64);
                const int s6 = __shfl(esrc, j + 6, 64), s7 = __shfl(esrc, j + 7, 64);
                const float m0 = __shfl(enm, j + 0, 64), m1 = __shfl(enm, j + 1, 64);
                const float m2 = __shfl(enm, j + 2, 64), m3 = __shfl(enm, j + 3, 64);
                const float m4 = __shfl(enm, j + 4, 64), m5 = __shfl(enm, j + 5, 64);
                const float m6 = __shfl(enm, j + 6, 64), m7 = __shfl(enm, j + 7, 64);
                const float4 v0 = Xq[(rowBase + s0) * 96u + q];
                const float4 v1 = Xq[(rowBase + s1) * 96u + q];
                const float4 v2 = Xq[(rowBase + s2) * 96u + q];
                const float4 v3 = Xq[(rowBase + s3) * 96u + q];
                const float4 v4 = Xq[(rowBase + s4) * 96u + q];
                const float4 v5 = Xq[(rowBase + s5) * 96u + q];
                const float4 v6 = Xq[(rowBase + s6) * 96u + q];
                const float4 v7 = Xq[(rowBase + s7) * 96u + q];
                a0.x += m0 * v0.x; a0.y += m0 * v0.y; a0.z += m0 * v0.z; a0.w += m0 * v0.w;
                a1.x += m1 * v1.x; a1.y += m1 * v1.y; a1.z += m1 * v1.z; a1.w += m1 * v1.w;
                a2.x += m2 * v2.x; a2.y += m2 * v2.y; a2.z += m2 * v2.z; a2.w += m2 * v2.w;
                a3.x += m3 * v3.x; a3.y += m3 * v3.y; a3.z += m3 * v3.z; a3.w += m3 * v3.w;
                a0.x += m4 * v4.x; a0.y += m4 * v4.y; a0.z += m4 * v4.z; a0.w += m4 * v4.w;
                a1.x += m5 * v5.x; a1.y += m5 * v5.y; a1.z += m5 * v5.z; a1.w += m5 * v5.w;
                a2.x += m6 * v6.x; a2.y += m6 * v6.y; a2.z += m6 * v6.z; a2.w += m6 * v6.w;
                a3.x += m7 * v7.x; a3.y += m7 * v7.y; a3.z += m7 * v7.z; a3.w += m7 * v7.w;
            }
            for (; j < cnt; j++) {
                const int s = __shfl(esrc, j, 64);
                const float m = __shfl(enm, j, 64);
                const float4 v = Xq[(rowBase + s) * 96u + q];
                a0.x += m * v.x; a0.y += m * v.y; a0.z += m * v.z; a0.w += m * v.w;
            }
        }
        a0.x += (a1.x + a2.x) + a3.x;
        a0.y += (a1.y + a2.y) + a3.y;
        a0.z += (a1.z + a2.z) + a3.z;
        a0.w += (a1.w + a2.w) + a3.w;
        sY4[b][q] = a0;
        __syncthreads();

        // ---- Phase 2: gates ----
#pragma unroll
        for (int bb = 0; bb < BDIM; bb++) {
            const float* yb = (const float*)sY4[bb];
            float z0 = bzo, z1 = bzo, h0 = bho, h1 = bho;
#pragma unroll
            for (int f = 0; f < FDIM; f++) {
                float ya = yb[f * TDIM + t0];
                float yc = yb[f * TDIM + t1];
                z0 += ya * wzr[f]; h0 += ya * whr[f];
                z1 += yc * wzr[f]; h1 += yc * whr[f];
            }
            float contrib = p0 * (1.f - sigm(z0)) * tanhf(h0)
                          + p1 * (1.f - sigm(z1)) * tanhf(h1);
            atomicAdd(&sAcc[bb][o], contrib);
        }
        __syncthreads();

        // ---- Phase 3: readout ----
        if (tid < BDIM * TDIM) {
            int ob = tid / TDIM, jj = tid - ob * TDIM;
            float v = sBout[jj];
#pragma unroll
            for (int o2 = 0; o2 < ODIM; o2++) {
                v += fmaxf(sAcc[ob][o2], 0.f) * sWout[o2 * TDIM + jj];
            }
            out[(unsigned)(ob * N + n) * TDIM + jj] = v;
        }
        __syncthreads();
    }
}

extern "C" void kernel_launch(void* const* d_in, const int* in_sizes, int n_in,
                              void* d_out, int out_size, void* d_ws, size_t ws_size,
                              hipStream_t stream) {
    const float* X    = (const float*)d_in[0];
    const int*   ei   = (const int*)d_in[1];
    const float* Wg_z = (const float*)d_in[2];
    const float* bg_z = (const float*)d_in[3];
    const float* Wg_h = (const float*)d_in[6];
    const float* bg_h = (const float*)d_in[7];
    const float* Wl_z = (const float*)d_in[8];
    const float* bl_z = (const float*)d_in[9];
    const float* Wl_h = (const float*)d_in[12];
    const float* bl_h = (const float*)d_in[13];
    const float* att  = (const float*)d_in[14];
    const float* Wout = (const float*)d_in[15];
    const float* bout = (const float*)d_in[16];
    float* out = (float*)d_out;

    const int E = in_sizes[1] / 2;
    const int N = in_sizes[0] / (BDIM * FDIM * TDIM);

    char* wp = (char*)d_ws;
    int* counts   = (int*)wp;   wp += (size_t)N * 4;
    int* fill     = (int*)wp;   wp += (size_t)N * 4;
    int* offs     = (int*)wp;   wp += (size_t)(N + 4) * 4;
    float* dis    = (float*)wp; wp += (size_t)N * 4;
    int2* csr     = (int2*)wp;  wp += (size_t)E * 8;
    float* Wz     = (float*)wp; wp += FDIM * ODIM * 4;
    float* Wh     = (float*)wp; wp += FDIM * ODIM * 4;
    float* bz     = (float*)wp; wp += ODIM * 4;
    float* bh     = (float*)wp; wp += ODIM * 4;
    float* probs  = (float*)wp; wp += 16 * 4;

    hipMemsetAsync(counts, 0, (size_t)2 * N * 4, stream);

    k_prep<<<1, 256, 0, stream>>>(Wg_z, bg_z, Wl_z, bl_z, Wg_h, bg_h, Wl_h, bl_h,
                                  att, Wz, bz, Wh, bh, probs);
    k_count<<<(E + 255) / 256, 256, 0, stream>>>(ei + E, counts, E);
    k_scan<<<1, 1024, 0, stream>>>(counts, offs, dis, N);
    k_scatter<<<(E + 255) / 256, 256, 0, stream>>>(ei, ei + E, offs, fill, dis, csr, E);

    int nBlocks = N < 2048 ? N : 2048;
    k_main<<<nBlocks, 384, 0, stream>>>(X, offs, csr, dis, Wz, bz, Wh, bh,
                                        probs, Wout, bout, out, N);
}